// Round 7
// baseline (1329.873 us; speedup 1.0000x reference)
//
#include <hip/hip_runtime.h>

#define N_LOC 100000
#define N_EVT 100000
#define N_EDGE 1600000
#define NB 391        // ceil(N_LOC/256) buckets of 256 dst values
#define BCAP 5120     // bucket capacity: avg 4096 + 16 sigma
#define TILE 4096     // edges per k_bin block (256 thr x 16)
#define CB 8          // rows per wave-batch in dense kernels

__device__ __forceinline__ unsigned bf16_rne(float x) {
    unsigned u = __float_as_uint(x);
    return (u + 0x7fffu + ((u >> 16) & 1u)) >> 16;
}
__device__ __forceinline__ float bf_lo(unsigned u) { return __uint_as_float(u << 16); }
__device__ __forceinline__ float bf_hi(unsigned u) { return __uint_as_float(u & 0xffff0000u); }

// ---------------------------------------------------------------------------
// K1: evt_x = relu(evt_feat @ W_evt + b_evt) -> packed bf16 [N_EVT x 32 uint]
// 8 rows per wave: weight fragment read ONCE per 8 rows (amortizes LDS);
// activation rows are wave-uniform loads (scalarizable to s_load).
// ---------------------------------------------------------------------------
__global__ __launch_bounds__(256, 4) void k_evt(const float* __restrict__ feat,
                                                const float* __restrict__ W,
                                                const float* __restrict__ b,
                                                unsigned* __restrict__ outb, int n) {
    __shared__ float4 sW[32 * 64];  // [j4][lane] = W rows 4j4..4j4+3, col lane
    const int t = threadIdx.x;
    for (int idx = t; idx < 128 * 64; idx += 256) {
        int j = idx >> 6, c = idx & 63;
        ((float*)&sW[(j >> 2) * 64 + c])[j & 3] = W[idx];
    }
    __syncthreads();
    const int lane = t & 63;
    const float bias = b[lane];
    const int wid = blockIdx.x * 4 + (t >> 6);
    const int nw = gridDim.x * 4;
    for (int base = wid * CB; base < n; base += nw * CB) {
        const int b0 = __builtin_amdgcn_readfirstlane(base);
        float o[CB];
#pragma unroll
        for (int r = 0; r < CB; ++r) o[r] = bias;
#pragma unroll
        for (int j4 = 0; j4 < 32; ++j4) {
            const float4 wv = sW[j4 * 64 + lane];
#pragma unroll
            for (int r = 0; r < CB; ++r) {
                float4 av = ((const float4*)(feat + (size_t)(b0 + r) * 128))[j4];
                o[r] = fmaf(av.x, wv.x, o[r]);
                o[r] = fmaf(av.y, wv.y, o[r]);
                o[r] = fmaf(av.z, wv.z, o[r]);
                o[r] = fmaf(av.w, wv.w, o[r]);
            }
        }
#pragma unroll
        for (int r = 0; r < CB; ++r) {
            float oc = fmaxf(o[r], 0.0f);
            int src = 2 * (lane & 31);
            float lo = __shfl(oc, src);
            float hi = __shfl(oc, src + 1);
            unsigned u = bf16_rne(lo) | (bf16_rne(hi) << 16);
            if (lane < 32) outb[(size_t)(b0 + r) * 32 + lane] = u;
        }
    }
}

// ---------------------------------------------------------------------------
// K2: loc_x = relu([loc_feat || emb[qid]] @ W_loc + b_loc)  [N_LOC x 64] fp32
// ---------------------------------------------------------------------------
__global__ __launch_bounds__(256, 4) void k_loc(const float* __restrict__ feat,
                                                const int* __restrict__ qid,
                                                const float* __restrict__ emb,
                                                const float* __restrict__ W,
                                                const float* __restrict__ b,
                                                float* __restrict__ out, int n) {
    __shared__ float4 sW[36 * 64];  // 36 KB
    const int t = threadIdx.x;
    for (int idx = t; idx < 144 * 64; idx += 256) {
        int j = idx >> 6, c = idx & 63;
        ((float*)&sW[(j >> 2) * 64 + c])[j & 3] = W[idx];
    }
    __syncthreads();
    const int lane = t & 63;
    const float bias = b[lane];
    const int wid = blockIdx.x * 4 + (t >> 6);
    const int nw = gridDim.x * 4;
    for (int base = wid * CB; base < n; base += nw * CB) {
        const int b0 = __builtin_amdgcn_readfirstlane(base);
        float o[CB];
#pragma unroll
        for (int r = 0; r < CB; ++r) o[r] = bias;
#pragma unroll
        for (int j4 = 0; j4 < 32; ++j4) {
            const float4 wv = sW[j4 * 64 + lane];
#pragma unroll
            for (int r = 0; r < CB; ++r) {
                float4 av = ((const float4*)(feat + (size_t)(b0 + r) * 128))[j4];
                o[r] = fmaf(av.x, wv.x, o[r]);
                o[r] = fmaf(av.y, wv.y, o[r]);
                o[r] = fmaf(av.z, wv.z, o[r]);
                o[r] = fmaf(av.w, wv.w, o[r]);
            }
        }
#pragma unroll
        for (int r = 0; r < CB; ++r) {
            const int q = qid[b0 + r];
            const float4* erow = (const float4*)(emb + (size_t)q * 16);
#pragma unroll
            for (int ji = 0; ji < 4; ++ji) {
                float4 av = erow[ji];
                float4 wv = sW[(32 + ji) * 64 + lane];
                o[r] = fmaf(av.x, wv.x, o[r]);
                o[r] = fmaf(av.y, wv.y, o[r]);
                o[r] = fmaf(av.z, wv.z, o[r]);
                o[r] = fmaf(av.w, wv.w, o[r]);
            }
            out[(size_t)(b0 + r) * 64 + lane] = fmaxf(o[r], 0.0f);
        }
    }
}

// ---------------------------------------------------------------------------
// k_bin: bucket edges by dst>>8 into fixed-capacity regions.
// ---------------------------------------------------------------------------
__global__ __launch_bounds__(256) void k_bin(const int* __restrict__ ei,
                                             int* __restrict__ bucket_cnt,
                                             uint2* __restrict__ binned, int n) {
    __shared__ int h[NB];
    __shared__ int base[NB];
    const int t = threadIdx.x;
    for (int i = t; i < NB; i += 256) h[i] = 0;
    __syncthreads();
    const int e0 = blockIdx.x * TILE;
    int src[16], dst[16], rnk[16];
#pragma unroll
    for (int j = 0; j < 16; ++j) {
        int e = e0 + j * 256 + t;
        if (e < n) {
            src[j] = ei[e];
            dst[j] = ei[n + e];
            rnk[j] = atomicAdd(&h[dst[j] >> 8], 1);
        }
    }
    __syncthreads();
    for (int i = t; i < NB; i += 256) {
        int c = h[i];
        base[i] = (c > 0) ? atomicAdd(&bucket_cnt[i], c) : 0;
    }
    __syncthreads();
#pragma unroll
    for (int j = 0; j < 16; ++j) {
        int e = e0 + j * 256 + t;
        if (e < n) {
            int b = dst[j] >> 8;
            int idx = base[b] + rnk[j];
            if (idx < BCAP)
                binned[(size_t)b * BCAP + idx] = make_uint2((unsigned)src[j], (unsigned)dst[j]);
        }
    }
}

// ---------------------------------------------------------------------------
// k_bscan: exclusive scan of the 391 bucket counts (single block).
// ---------------------------------------------------------------------------
__global__ __launch_bounds__(512) void k_bscan(const int* __restrict__ bucket_cnt,
                                               int* __restrict__ csr_off) {
    __shared__ int sd[512];
    const int t = threadIdx.x;
    int v = (t < NB) ? min(bucket_cnt[t], BCAP) : 0;
    sd[t] = v;
    __syncthreads();
    for (int off = 1; off < 512; off <<= 1) {
        int x = (t >= off) ? sd[t - off] : 0;
        __syncthreads();
        sd[t] += x;
        __syncthreads();
    }
    if (t < NB) csr_off[t] = sd[t] - v;
    if (t == NB - 1) csr_off[NB] = sd[t];
}

// ---------------------------------------------------------------------------
// k_bfill: one block per bucket: LDS degree hist -> scan -> deg/row_ex, then
// scatter csr with LDS cursors (writes confined to ~16KB window).
// ---------------------------------------------------------------------------
__global__ __launch_bounds__(256) void k_bfill(const int* __restrict__ bucket_cnt,
                                               const int* __restrict__ csr_off,
                                               const uint2* __restrict__ binned,
                                               int* __restrict__ deg,
                                               int* __restrict__ row_ex,
                                               int* __restrict__ csr) {
    __shared__ int degl[256];
    __shared__ int sc[256];
    __shared__ int cur[256];
    const int b = blockIdx.x;
    const int t = threadIdx.x;
    const int nb = min(bucket_cnt[b], BCAP);
    const uint2* bin = binned + (size_t)b * BCAP;
    degl[t] = 0;
    __syncthreads();
    for (int i = t; i < nb; i += 256)
        atomicAdd(&degl[bin[i].y & 255], 1);
    __syncthreads();
    const int v = degl[t];
    sc[t] = v;
    __syncthreads();
    for (int off = 1; off < 256; off <<= 1) {
        int x = (t >= off) ? sc[t - off] : 0;
        __syncthreads();
        sc[t] += x;
        __syncthreads();
    }
    const int ex = csr_off[b] + sc[t] - v;
    const int loc = b * 256 + t;
    if (loc < N_LOC) { deg[loc] = v; row_ex[loc] = ex; }
    cur[t] = ex;
    __syncthreads();
    for (int i = t; i < nb; i += 256) {
        uint2 u = bin[i];
        int pos = atomicAdd(&cur[u.y & 255], 1);
        csr[pos] = (int)u.x;
    }
}

// ---------------------------------------------------------------------------
// K4: mean[loc] from bf16-packed evt rows. One wave per loc. Lean: no LDS,
// ~30 VGPR, launch_bounds(256,8) -> full occupancy for the latency-bound
// gather. 2 edges per load instr (32 lanes/row, 2 chans/lane), unroll 8.
// ---------------------------------------------------------------------------
__global__ __launch_bounds__(256, 8) void k_aggr(const unsigned* __restrict__ evtb,
                                                 const int* __restrict__ row_ex,
                                                 const int* __restrict__ deg,
                                                 const int* __restrict__ csr,
                                                 float* __restrict__ meanb, int n) {
    const int lane = threadIdx.x & 63;
    const int wid = (blockIdx.x * 256 + threadIdx.x) >> 6;
    if (wid >= n) return;
    const int beg = row_ex[wid];
    const int cnt = deg[wid];
    const int half = lane >> 5;   // which edge of the pair
    const int c = lane & 31;      // channel-pair index
    float a0 = 0.0f, a1 = 0.0f;
    int i = 0;
    for (; i + 8 <= cnt; i += 8) {
        const int bb = beg + i + half;
        int s0 = csr[bb + 0];
        int s1 = csr[bb + 2];
        int s2 = csr[bb + 4];
        int s3 = csr[bb + 6];
        unsigned u0 = evtb[(size_t)s0 * 32 + c];
        unsigned u1 = evtb[(size_t)s1 * 32 + c];
        unsigned u2 = evtb[(size_t)s2 * 32 + c];
        unsigned u3 = evtb[(size_t)s3 * 32 + c];
        a0 += (bf_lo(u0) + bf_lo(u1)) + (bf_lo(u2) + bf_lo(u3));
        a1 += (bf_hi(u0) + bf_hi(u1)) + (bf_hi(u2) + bf_hi(u3));
    }
    for (; i < cnt; i += 2) {
        int idx = i + half;
        if (idx < cnt) {
            int s = csr[beg + idx];
            unsigned u = evtb[(size_t)s * 32 + c];
            a0 += bf_lo(u);
            a1 += bf_hi(u);
        }
    }
    a0 += __shfl_xor(a0, 32);
    a1 += __shfl_xor(a1, 32);
    const float inv = 1.0f / (float)max(cnt, 1);
    if (lane < 32) {
        float2 mv = make_float2(a0 * inv, a1 * inv);
        *((float2*)(meanb + (size_t)wid * 64 + 2 * c)) = mv;
    }
}

// ---------------------------------------------------------------------------
// K5: x2 = relu(mean @ W_l + b_l + locx @ W_r); h = relu(x2 @ W_h1 + b_h1);
//     out = h @ W_h2 + b_h2.  8 locs per wave (weights read once per 8).
// ---------------------------------------------------------------------------
__global__ __launch_bounds__(256, 3) void k_comb(
    const float* __restrict__ meanb, const float* __restrict__ locx,
    const float* __restrict__ W_l, const float* __restrict__ b_l,
    const float* __restrict__ W_r,
    const float* __restrict__ W_h1, const float* __restrict__ b_h1,
    const float* __restrict__ W_h2, const float* __restrict__ b_h2,
    float* __restrict__ out, int n)
{
    __shared__ float4 sWl[16 * 64];   // 16 KB
    __shared__ float4 sWr[16 * 64];   // 16 KB
    __shared__ float4 sWh1[16 * 32];  // 8 KB
    __shared__ float  sWh2[32];
    __shared__ float  sx2[4][CB][64]; // 8 KB
    const int t = threadIdx.x;
    for (int idx = t; idx < 64 * 64; idx += 256) {
        int j = idx >> 6, c = idx & 63;
        ((float*)&sWl[(j >> 2) * 64 + c])[j & 3] = W_l[idx];
        ((float*)&sWr[(j >> 2) * 64 + c])[j & 3] = W_r[idx];
    }
    for (int idx = t; idx < 64 * 32; idx += 256) {
        int j = idx >> 5, k = idx & 31;
        ((float*)&sWh1[(j >> 2) * 32 + k])[j & 3] = W_h1[idx];
    }
    if (t < 32) sWh2[t] = W_h2[t];
    __syncthreads();
    const int lane = t & 63;
    const int w = t >> 6;
    const int kk = lane & 31;
    const float bl = b_l[lane];
    const float bh1 = b_h1[kk];
    const float bh2 = b_h2[0];
    const int wid = blockIdx.x * 4 + w;
    const int nw = gridDim.x * 4;
    for (int base = wid * CB; base < n; base += nw * CB) {
        const int b0 = __builtin_amdgcn_readfirstlane(base);
        float o[CB];
#pragma unroll
        for (int r = 0; r < CB; ++r) o[r] = bl;
#pragma unroll
        for (int j4 = 0; j4 < 16; ++j4) {
            const float4 wl = sWl[j4 * 64 + lane];
            const float4 wr = sWr[j4 * 64 + lane];
#pragma unroll
            for (int r = 0; r < CB; ++r) {
                float4 m4 = ((const float4*)(meanb + (size_t)(b0 + r) * 64))[j4];
                float4 x4 = ((const float4*)(locx + (size_t)(b0 + r) * 64))[j4];
                o[r] = fmaf(m4.x, wl.x, o[r]); o[r] = fmaf(x4.x, wr.x, o[r]);
                o[r] = fmaf(m4.y, wl.y, o[r]); o[r] = fmaf(x4.y, wr.y, o[r]);
                o[r] = fmaf(m4.z, wl.z, o[r]); o[r] = fmaf(x4.z, wr.z, o[r]);
                o[r] = fmaf(m4.w, wl.w, o[r]); o[r] = fmaf(x4.w, wr.w, o[r]);
            }
        }
#pragma unroll
        for (int r = 0; r < CB; ++r) sx2[w][r][lane] = fmaxf(o[r], 0.0f);
        float hv[CB];
#pragma unroll
        for (int r = 0; r < CB; ++r) hv[r] = bh1;
#pragma unroll
        for (int j4 = 0; j4 < 16; ++j4) {
            const float4 wh = sWh1[j4 * 32 + kk];
#pragma unroll
            for (int r = 0; r < CB; ++r) {
                float4 a = ((const float4*)sx2[w][r])[j4];
                hv[r] = fmaf(a.x, wh.x, hv[r]);
                hv[r] = fmaf(a.y, wh.y, hv[r]);
                hv[r] = fmaf(a.z, wh.z, hv[r]);
                hv[r] = fmaf(a.w, wh.w, hv[r]);
            }
        }
#pragma unroll
        for (int r = 0; r < CB; ++r) {
            float v = fmaxf(hv[r], 0.0f) * sWh2[kk];
#pragma unroll
            for (int m = 16; m >= 1; m >>= 1) v += __shfl_xor(v, m);
            if (lane == 0) out[base + r] = v + bh2;
        }
    }
}

// ---------------------------------------------------------------------------
extern "C" void kernel_launch(void* const* d_in, const int* in_sizes, int n_in,
                              void* d_out, int out_size, void* d_ws, size_t ws_size,
                              hipStream_t stream) {
    const float* loc_feat = (const float*)d_in[0];
    const float* evt_feat = (const float*)d_in[1];
    const int*   qid      = (const int*)d_in[2];
    const int*   ei       = (const int*)d_in[3];
    const float* emb      = (const float*)d_in[4];
    const float* W_loc    = (const float*)d_in[5];
    const float* b_loc    = (const float*)d_in[6];
    const float* W_evt    = (const float*)d_in[7];
    const float* b_evt    = (const float*)d_in[8];
    const float* W_l      = (const float*)d_in[9];
    const float* b_l      = (const float*)d_in[10];
    const float* W_r      = (const float*)d_in[11];
    const float* W_h1     = (const float*)d_in[12];
    const float* b_h1     = (const float*)d_in[13];
    const float* W_h2     = (const float*)d_in[14];
    const float* b_h2     = (const float*)d_in[15];
    float* out = (float*)d_out;

    char* ws = (char*)d_ws;
    size_t off = 0;
    auto alloc = [&](size_t bytes) -> void* {
        void* p = ws + off;
        off += (bytes + 255) & ~(size_t)255;
        return p;
    };
    unsigned* evtb  = (unsigned*)alloc((size_t)N_EVT * 32 * 4);      // bf16-packed evt_x (12.8 MB)
    float* loc_x    = (float*)alloc((size_t)N_LOC * 64 * 4);         // 25.6 MB
    float* meanb    = (float*)alloc((size_t)N_LOC * 64 * 4);         // 25.6 MB
    float* scratch  = (float*)alloc((size_t)NB * BCAP * 8);          // binned region (16 MB)
    int*   deg      = (int*)alloc((size_t)N_LOC * 4);
    int*   row_ex   = (int*)alloc((size_t)(N_LOC + 1) * 4);
    int*   csr      = (int*)alloc((size_t)N_EDGE * 4);
    int*   bucket_cnt = (int*)alloc((size_t)NB * 4);
    int*   csr_off  = (int*)alloc((size_t)(NB + 1) * 4);
    uint2* binned   = (uint2*)scratch;
    (void)ws_size; (void)in_sizes; (void)n_in; (void)out_size;

    hipMemsetAsync(bucket_cnt, 0, (size_t)NB * 4, stream);

    // 12500 wave-batches of 8 rows -> 3125 blocks for the dense kernels
    k_evt<<<3125, 256, 0, stream>>>(evt_feat, W_evt, b_evt, evtb, N_EVT);
    k_loc<<<3125, 256, 0, stream>>>(loc_feat, qid, emb, W_loc, b_loc, loc_x, N_LOC);
    k_bin<<<(N_EDGE + TILE - 1) / TILE, 256, 0, stream>>>(ei, bucket_cnt, binned, N_EDGE);
    k_bscan<<<1, 512, 0, stream>>>(bucket_cnt, csr_off);
    k_bfill<<<NB, 256, 0, stream>>>(bucket_cnt, csr_off, binned, deg, row_ex, csr);
    k_aggr<<<N_LOC / 4, 256, 0, stream>>>(evtb, row_ex, deg, csr, meanb, N_LOC);
    k_comb<<<3125, 256, 0, stream>>>(meanb, loc_x, W_l, b_l, W_r, W_h1, b_h1, W_h2, b_h2,
                                     out, N_LOC);
}

// Round 8
// 296.686 us; speedup vs baseline: 4.4824x; 4.4824x over previous
//
#include <hip/hip_runtime.h>

#define N_LOC 100000
#define N_EVT 100000
#define N_EDGE 1600000
#define NB 391        // ceil(N_LOC/256) buckets of 256 dst values
#define BCAP 5120     // bucket capacity: avg 4096 + 16 sigma
#define TILE 4096     // edges per k_bin block (256 thr x 16)
#define CB 4          // rows per wave-batch in dense kernels (bounded live set)

__device__ __forceinline__ unsigned bf16_rne(float x) {
    unsigned u = __float_as_uint(x);
    return (u + 0x7fffu + ((u >> 16) & 1u)) >> 16;
}
__device__ __forceinline__ float bf_lo(unsigned u) { return __uint_as_float(u << 16); }
__device__ __forceinline__ float bf_hi(unsigned u) { return __uint_as_float(u & 0xffff0000u); }

// ---------------------------------------------------------------------------
// K1: evt_x = relu(evt_feat @ W_evt + b_evt) -> packed bf16 [N_EVT x 32 uint]
// CB=4 rows/wave; k-loop = unroll-1 outer over 4-frag chunks:
// live set = 4 weight float4 (LDS) + 16 activation float4 (uniform loads).
// ---------------------------------------------------------------------------
__global__ __launch_bounds__(256) void k_evt(const float* __restrict__ feat,
                                             const float* __restrict__ W,
                                             const float* __restrict__ b,
                                             unsigned* __restrict__ outb, int n) {
    __shared__ float4 sW[32 * 64];  // [j4][lane] = W rows 4j4..4j4+3, col lane (32 KB)
    const int t = threadIdx.x;
    for (int idx = t; idx < 128 * 64; idx += 256) {
        int j = idx >> 6, c = idx & 63;
        ((float*)&sW[(j >> 2) * 64 + c])[j & 3] = W[idx];
    }
    __syncthreads();
    const int lane = t & 63;
    const float bias = b[lane];
    const int wid = blockIdx.x * 4 + (t >> 6);
    const int nw = gridDim.x * 4;
    for (int base = wid * CB; base < n; base += nw * CB) {
        const int b0 = __builtin_amdgcn_readfirstlane(base);
        const float4* r0 = (const float4*)(feat + (size_t)(b0 + 0) * 128);
        const float4* r1 = (const float4*)(feat + (size_t)(b0 + 1) * 128);
        const float4* r2 = (const float4*)(feat + (size_t)(b0 + 2) * 128);
        const float4* r3 = (const float4*)(feat + (size_t)(b0 + 3) * 128);
        float o0 = bias, o1 = bias, o2 = bias, o3 = bias;
#pragma unroll 1
        for (int jo = 0; jo < 32; jo += 4) {
            float4 w0 = sW[(jo + 0) * 64 + lane];
            float4 w1 = sW[(jo + 1) * 64 + lane];
            float4 w2 = sW[(jo + 2) * 64 + lane];
            float4 w3 = sW[(jo + 3) * 64 + lane];
#define EVT_ROW(rp, acc)                                                        \
            {                                                                   \
                float4 a0 = rp[jo + 0], a1 = rp[jo + 1];                        \
                float4 a2 = rp[jo + 2], a3 = rp[jo + 3];                        \
                acc = fmaf(a0.x, w0.x, acc); acc = fmaf(a0.y, w0.y, acc);       \
                acc = fmaf(a0.z, w0.z, acc); acc = fmaf(a0.w, w0.w, acc);       \
                acc = fmaf(a1.x, w1.x, acc); acc = fmaf(a1.y, w1.y, acc);       \
                acc = fmaf(a1.z, w1.z, acc); acc = fmaf(a1.w, w1.w, acc);       \
                acc = fmaf(a2.x, w2.x, acc); acc = fmaf(a2.y, w2.y, acc);       \
                acc = fmaf(a2.z, w2.z, acc); acc = fmaf(a2.w, w2.w, acc);       \
                acc = fmaf(a3.x, w3.x, acc); acc = fmaf(a3.y, w3.y, acc);       \
                acc = fmaf(a3.z, w3.z, acc); acc = fmaf(a3.w, w3.w, acc);       \
            }
            EVT_ROW(r0, o0) EVT_ROW(r1, o1) EVT_ROW(r2, o2) EVT_ROW(r3, o3)
#undef EVT_ROW
        }
        const int c = lane & 31;
        float oc, lo, hi; unsigned u;
        oc = fmaxf(o0, 0.0f); lo = __shfl(oc, 2 * c); hi = __shfl(oc, 2 * c + 1);
        u = bf16_rne(lo) | (bf16_rne(hi) << 16);
        if (lane < 32) outb[(size_t)(b0 + 0) * 32 + c] = u;
        oc = fmaxf(o1, 0.0f); lo = __shfl(oc, 2 * c); hi = __shfl(oc, 2 * c + 1);
        u = bf16_rne(lo) | (bf16_rne(hi) << 16);
        if (lane < 32) outb[(size_t)(b0 + 1) * 32 + c] = u;
        oc = fmaxf(o2, 0.0f); lo = __shfl(oc, 2 * c); hi = __shfl(oc, 2 * c + 1);
        u = bf16_rne(lo) | (bf16_rne(hi) << 16);
        if (lane < 32) outb[(size_t)(b0 + 2) * 32 + c] = u;
        oc = fmaxf(o3, 0.0f); lo = __shfl(oc, 2 * c); hi = __shfl(oc, 2 * c + 1);
        u = bf16_rne(lo) | (bf16_rne(hi) << 16);
        if (lane < 32) outb[(size_t)(b0 + 3) * 32 + c] = u;
    }
}

// ---------------------------------------------------------------------------
// K2: loc_x = relu([loc_feat || emb[qid]] @ W_loc + b_loc)  [N_LOC x 64] fp32
// ---------------------------------------------------------------------------
__global__ __launch_bounds__(256) void k_loc(const float* __restrict__ feat,
                                             const int* __restrict__ qid,
                                             const float* __restrict__ emb,
                                             const float* __restrict__ W,
                                             const float* __restrict__ b,
                                             float* __restrict__ out, int n) {
    __shared__ float4 sW[36 * 64];  // 36 KB
    const int t = threadIdx.x;
    for (int idx = t; idx < 144 * 64; idx += 256) {
        int j = idx >> 6, c = idx & 63;
        ((float*)&sW[(j >> 2) * 64 + c])[j & 3] = W[idx];
    }
    __syncthreads();
    const int lane = t & 63;
    const float bias = b[lane];
    const int wid = blockIdx.x * 4 + (t >> 6);
    const int nw = gridDim.x * 4;
    for (int base = wid * CB; base < n; base += nw * CB) {
        const int b0 = __builtin_amdgcn_readfirstlane(base);
        const float4* r0 = (const float4*)(feat + (size_t)(b0 + 0) * 128);
        const float4* r1 = (const float4*)(feat + (size_t)(b0 + 1) * 128);
        const float4* r2 = (const float4*)(feat + (size_t)(b0 + 2) * 128);
        const float4* r3 = (const float4*)(feat + (size_t)(b0 + 3) * 128);
        float o0 = bias, o1 = bias, o2 = bias, o3 = bias;
#pragma unroll 1
        for (int jo = 0; jo < 32; jo += 4) {
            float4 w0 = sW[(jo + 0) * 64 + lane];
            float4 w1 = sW[(jo + 1) * 64 + lane];
            float4 w2 = sW[(jo + 2) * 64 + lane];
            float4 w3 = sW[(jo + 3) * 64 + lane];
#define LOC_ROW(rp, acc)                                                        \
            {                                                                   \
                float4 a0 = rp[jo + 0], a1 = rp[jo + 1];                        \
                float4 a2 = rp[jo + 2], a3 = rp[jo + 3];                        \
                acc = fmaf(a0.x, w0.x, acc); acc = fmaf(a0.y, w0.y, acc);       \
                acc = fmaf(a0.z, w0.z, acc); acc = fmaf(a0.w, w0.w, acc);       \
                acc = fmaf(a1.x, w1.x, acc); acc = fmaf(a1.y, w1.y, acc);       \
                acc = fmaf(a1.z, w1.z, acc); acc = fmaf(a1.w, w1.w, acc);       \
                acc = fmaf(a2.x, w2.x, acc); acc = fmaf(a2.y, w2.y, acc);       \
                acc = fmaf(a2.z, w2.z, acc); acc = fmaf(a2.w, w2.w, acc);       \
                acc = fmaf(a3.x, w3.x, acc); acc = fmaf(a3.y, w3.y, acc);       \
                acc = fmaf(a3.z, w3.z, acc); acc = fmaf(a3.w, w3.w, acc);       \
            }
            LOC_ROW(r0, o0) LOC_ROW(r1, o1) LOC_ROW(r2, o2) LOC_ROW(r3, o3)
#undef LOC_ROW
        }
        // embedding tail: dims 128..143 (4 float4 frags), per row
#pragma unroll
        for (int r = 0; r < CB; ++r) {
            const int q = qid[b0 + r];
            const float4* erow = (const float4*)(emb + (size_t)q * 16);
            float acc = (r == 0) ? o0 : (r == 1) ? o1 : (r == 2) ? o2 : o3;
#pragma unroll
            for (int ji = 0; ji < 4; ++ji) {
                float4 av = erow[ji];
                float4 wv = sW[(32 + ji) * 64 + lane];
                acc = fmaf(av.x, wv.x, acc);
                acc = fmaf(av.y, wv.y, acc);
                acc = fmaf(av.z, wv.z, acc);
                acc = fmaf(av.w, wv.w, acc);
            }
            out[(size_t)(b0 + r) * 64 + lane] = fmaxf(acc, 0.0f);
        }
    }
}

// ---------------------------------------------------------------------------
// k_bin: bucket edges by dst>>8; payload packed to 4B: src(24b) | dstlow(8b).
// ---------------------------------------------------------------------------
__global__ __launch_bounds__(256) void k_bin(const int* __restrict__ ei,
                                             int* __restrict__ bucket_cnt,
                                             unsigned* __restrict__ binned, int n) {
    __shared__ int h[NB];
    __shared__ int base[NB];
    const int t = threadIdx.x;
    for (int i = t; i < NB; i += 256) h[i] = 0;
    __syncthreads();
    const int e0 = blockIdx.x * TILE;
    int src[16], dst[16], rnk[16];
#pragma unroll
    for (int j = 0; j < 16; ++j) {
        int e = e0 + j * 256 + t;
        if (e < n) {
            src[j] = ei[e];
            dst[j] = ei[n + e];
            rnk[j] = atomicAdd(&h[dst[j] >> 8], 1);
        }
    }
    __syncthreads();
    for (int i = t; i < NB; i += 256) {
        int c = h[i];
        base[i] = (c > 0) ? atomicAdd(&bucket_cnt[i], c) : 0;
    }
    __syncthreads();
#pragma unroll
    for (int j = 0; j < 16; ++j) {
        int e = e0 + j * 256 + t;
        if (e < n) {
            int b = dst[j] >> 8;
            int idx = base[b] + rnk[j];
            if (idx < BCAP)
                binned[(size_t)b * BCAP + idx] =
                    (unsigned)src[j] | ((unsigned)(dst[j] & 255) << 24);
        }
    }
}

// ---------------------------------------------------------------------------
// k_bscan: exclusive scan of the 391 bucket counts (single block).
// ---------------------------------------------------------------------------
__global__ __launch_bounds__(512) void k_bscan(const int* __restrict__ bucket_cnt,
                                               int* __restrict__ csr_off) {
    __shared__ int sd[512];
    const int t = threadIdx.x;
    int v = (t < NB) ? min(bucket_cnt[t], BCAP) : 0;
    sd[t] = v;
    __syncthreads();
    for (int off = 1; off < 512; off <<= 1) {
        int x = (t >= off) ? sd[t - off] : 0;
        __syncthreads();
        sd[t] += x;
        __syncthreads();
    }
    if (t < NB) csr_off[t] = sd[t] - v;
    if (t == NB - 1) csr_off[NB] = sd[t];
}

// ---------------------------------------------------------------------------
// k_bfill: one block per bucket: LDS degree hist -> scan -> deg/row_ex, then
// scatter csr with LDS cursors (writes confined to ~16KB window).
// ---------------------------------------------------------------------------
__global__ __launch_bounds__(256) void k_bfill(const int* __restrict__ bucket_cnt,
                                               const int* __restrict__ csr_off,
                                               const unsigned* __restrict__ binned,
                                               int* __restrict__ deg,
                                               int* __restrict__ row_ex,
                                               int* __restrict__ csr) {
    __shared__ int degl[256];
    __shared__ int sc[256];
    __shared__ int cur[256];
    const int b = blockIdx.x;
    const int t = threadIdx.x;
    const int nb = min(bucket_cnt[b], BCAP);
    const unsigned* bin = binned + (size_t)b * BCAP;
    degl[t] = 0;
    __syncthreads();
    for (int i = t; i < nb; i += 256)
        atomicAdd(&degl[bin[i] >> 24], 1);
    __syncthreads();
    const int v = degl[t];
    sc[t] = v;
    __syncthreads();
    for (int off = 1; off < 256; off <<= 1) {
        int x = (t >= off) ? sc[t - off] : 0;
        __syncthreads();
        sc[t] += x;
        __syncthreads();
    }
    const int ex = csr_off[b] + sc[t] - v;
    const int loc = b * 256 + t;
    if (loc < N_LOC) { deg[loc] = v; row_ex[loc] = ex; }
    cur[t] = ex;
    __syncthreads();
    for (int i = t; i < nb; i += 256) {
        unsigned u = bin[i];
        int pos = atomicAdd(&cur[u >> 24], 1);
        csr[pos] = (int)(u & 0x00FFFFFFu);
    }
}

// ---------------------------------------------------------------------------
// K4: mean[loc] from bf16-packed evt rows. One wave per loc. No LDS, lean
// VGPRs, launch_bounds(256,8) -> full occupancy for the latency-bound gather.
// 2 edges per load instr (32 lanes/row, 2 chans/lane), unroll 8 deep.
// ---------------------------------------------------------------------------
__global__ __launch_bounds__(256, 8) void k_aggr(const unsigned* __restrict__ evtb,
                                                 const int* __restrict__ row_ex,
                                                 const int* __restrict__ deg,
                                                 const int* __restrict__ csr,
                                                 float* __restrict__ meanb, int n) {
    const int lane = threadIdx.x & 63;
    const int wid = (blockIdx.x * 256 + threadIdx.x) >> 6;
    if (wid >= n) return;
    const int beg = row_ex[wid];
    const int cnt = deg[wid];
    const int half = lane >> 5;   // which edge of the pair
    const int c = lane & 31;      // channel-pair index
    float a0 = 0.0f, a1 = 0.0f;
    int i = 0;
    for (; i + 8 <= cnt; i += 8) {
        const int bb = beg + i + half;
        int s0 = csr[bb + 0];
        int s1 = csr[bb + 2];
        int s2 = csr[bb + 4];
        int s3 = csr[bb + 6];
        unsigned u0 = evtb[(size_t)s0 * 32 + c];
        unsigned u1 = evtb[(size_t)s1 * 32 + c];
        unsigned u2 = evtb[(size_t)s2 * 32 + c];
        unsigned u3 = evtb[(size_t)s3 * 32 + c];
        a0 += (bf_lo(u0) + bf_lo(u1)) + (bf_lo(u2) + bf_lo(u3));
        a1 += (bf_hi(u0) + bf_hi(u1)) + (bf_hi(u2) + bf_hi(u3));
    }
    for (; i < cnt; i += 2) {
        int idx = i + half;
        if (idx < cnt) {
            int s = csr[beg + idx];
            unsigned u = evtb[(size_t)s * 32 + c];
            a0 += bf_lo(u);
            a1 += bf_hi(u);
        }
    }
    a0 += __shfl_xor(a0, 32);
    a1 += __shfl_xor(a1, 32);
    const float inv = 1.0f / (float)max(cnt, 1);
    if (lane < 32) {
        float2 mv = make_float2(a0 * inv, a1 * inv);
        *((float2*)(meanb + (size_t)wid * 64 + 2 * c)) = mv;
    }
}

// ---------------------------------------------------------------------------
// K5: x2 = relu(mean @ W_l + b_l + locx @ W_r); h = relu(x2 @ W_h1 + b_h1);
//     out = h @ W_h2 + b_h2.  CB=4 locs/wave, k-loop unroll-1 in chunks of 2.
// ---------------------------------------------------------------------------
__global__ __launch_bounds__(256) void k_comb(
    const float* __restrict__ meanb, const float* __restrict__ locx,
    const float* __restrict__ W_l, const float* __restrict__ b_l,
    const float* __restrict__ W_r,
    const float* __restrict__ W_h1, const float* __restrict__ b_h1,
    const float* __restrict__ W_h2, const float* __restrict__ b_h2,
    float* __restrict__ out, int n)
{
    __shared__ float4 sWl[16 * 64];   // 16 KB
    __shared__ float4 sWr[16 * 64];   // 16 KB
    __shared__ float4 sWh1[16 * 32];  // 8 KB
    __shared__ float  sWh2[32];
    __shared__ float  sx2[4][CB][64]; // 4 KB
    const int t = threadIdx.x;
    for (int idx = t; idx < 64 * 64; idx += 256) {
        int j = idx >> 6, c = idx & 63;
        ((float*)&sWl[(j >> 2) * 64 + c])[j & 3] = W_l[idx];
        ((float*)&sWr[(j >> 2) * 64 + c])[j & 3] = W_r[idx];
    }
    for (int idx = t; idx < 64 * 32; idx += 256) {
        int j = idx >> 5, k = idx & 31;
        ((float*)&sWh1[(j >> 2) * 32 + k])[j & 3] = W_h1[idx];
    }
    if (t < 32) sWh2[t] = W_h2[t];
    __syncthreads();
    const int lane = t & 63;
    const int w = t >> 6;
    const int kk = lane & 31;
    const float bl = b_l[lane];
    const float bh1 = b_h1[kk];
    const float bh2 = b_h2[0];
    const int wid = blockIdx.x * 4 + w;
    const int nw = gridDim.x * 4;
    for (int base = wid * CB; base < n; base += nw * CB) {
        const int b0 = __builtin_amdgcn_readfirstlane(base);
        const float4* m0 = (const float4*)(meanb + (size_t)(b0 + 0) * 64);
        const float4* m1 = (const float4*)(meanb + (size_t)(b0 + 1) * 64);
        const float4* m2 = (const float4*)(meanb + (size_t)(b0 + 2) * 64);
        const float4* m3 = (const float4*)(meanb + (size_t)(b0 + 3) * 64);
        const float4* x0 = (const float4*)(locx + (size_t)(b0 + 0) * 64);
        const float4* x1 = (const float4*)(locx + (size_t)(b0 + 1) * 64);
        const float4* x2p = (const float4*)(locx + (size_t)(b0 + 2) * 64);
        const float4* x3 = (const float4*)(locx + (size_t)(b0 + 3) * 64);
        float o0 = bl, o1 = bl, o2 = bl, o3 = bl;
#pragma unroll 1
        for (int jo = 0; jo < 16; jo += 2) {
            float4 wl0 = sWl[(jo + 0) * 64 + lane];
            float4 wl1 = sWl[(jo + 1) * 64 + lane];
            float4 wr0 = sWr[(jo + 0) * 64 + lane];
            float4 wr1 = sWr[(jo + 1) * 64 + lane];
#define COMB_ROW(mp, xp, acc)                                                   \
            {                                                                   \
                float4 ma = mp[jo + 0], mb = mp[jo + 1];                        \
                float4 xa = xp[jo + 0], xb = xp[jo + 1];                        \
                acc = fmaf(ma.x, wl0.x, acc); acc = fmaf(xa.x, wr0.x, acc);     \
                acc = fmaf(ma.y, wl0.y, acc); acc = fmaf(xa.y, wr0.y, acc);     \
                acc = fmaf(ma.z, wl0.z, acc); acc = fmaf(xa.z, wr0.z, acc);     \
                acc = fmaf(ma.w, wl0.w, acc); acc = fmaf(xa.w, wr0.w, acc);     \
                acc = fmaf(mb.x, wl1.x, acc); acc = fmaf(xb.x, wr1.x, acc);     \
                acc = fmaf(mb.y, wl1.y, acc); acc = fmaf(xb.y, wr1.y, acc);     \
                acc = fmaf(mb.z, wl1.z, acc); acc = fmaf(xb.z, wr1.z, acc);     \
                acc = fmaf(mb.w, wl1.w, acc); acc = fmaf(xb.w, wr1.w, acc);     \
            }
            COMB_ROW(m0, x0, o0) COMB_ROW(m1, x1, o1)
            COMB_ROW(m2, x2p, o2) COMB_ROW(m3, x3, o3)
#undef COMB_ROW
        }
        sx2[w][0][lane] = fmaxf(o0, 0.0f);
        sx2[w][1][lane] = fmaxf(o1, 0.0f);
        sx2[w][2][lane] = fmaxf(o2, 0.0f);
        sx2[w][3][lane] = fmaxf(o3, 0.0f);
        float h0 = bh1, h1 = bh1, h2 = bh1, h3 = bh1;
#pragma unroll 1
        for (int j4 = 0; j4 < 16; ++j4) {
            float4 wh = sWh1[j4 * 32 + kk];
            float4 a0 = ((const float4*)sx2[w][0])[j4];
            float4 a1 = ((const float4*)sx2[w][1])[j4];
            float4 a2 = ((const float4*)sx2[w][2])[j4];
            float4 a3 = ((const float4*)sx2[w][3])[j4];
            h0 = fmaf(a0.x, wh.x, h0); h0 = fmaf(a0.y, wh.y, h0);
            h0 = fmaf(a0.z, wh.z, h0); h0 = fmaf(a0.w, wh.w, h0);
            h1 = fmaf(a1.x, wh.x, h1); h1 = fmaf(a1.y, wh.y, h1);
            h1 = fmaf(a1.z, wh.z, h1); h1 = fmaf(a1.w, wh.w, h1);
            h2 = fmaf(a2.x, wh.x, h2); h2 = fmaf(a2.y, wh.y, h2);
            h2 = fmaf(a2.z, wh.z, h2); h2 = fmaf(a2.w, wh.w, h2);
            h3 = fmaf(a3.x, wh.x, h3); h3 = fmaf(a3.y, wh.y, h3);
            h3 = fmaf(a3.z, wh.z, h3); h3 = fmaf(a3.w, wh.w, h3);
        }
        const float w2 = sWh2[kk];
        float v0 = fmaxf(h0, 0.0f) * w2;
        float v1 = fmaxf(h1, 0.0f) * w2;
        float v2 = fmaxf(h2, 0.0f) * w2;
        float v3 = fmaxf(h3, 0.0f) * w2;
#pragma unroll
        for (int m = 16; m >= 1; m >>= 1) {
            v0 += __shfl_xor(v0, m);
            v1 += __shfl_xor(v1, m);
            v2 += __shfl_xor(v2, m);
            v3 += __shfl_xor(v3, m);
        }
        if (lane == 0) {
            out[base + 0] = v0 + bh2;
            out[base + 1] = v1 + bh2;
            out[base + 2] = v2 + bh2;
            out[base + 3] = v3 + bh2;
        }
    }
}

// ---------------------------------------------------------------------------
extern "C" void kernel_launch(void* const* d_in, const int* in_sizes, int n_in,
                              void* d_out, int out_size, void* d_ws, size_t ws_size,
                              hipStream_t stream) {
    const float* loc_feat = (const float*)d_in[0];
    const float* evt_feat = (const float*)d_in[1];
    const int*   qid      = (const int*)d_in[2];
    const int*   ei       = (const int*)d_in[3];
    const float* emb      = (const float*)d_in[4];
    const float* W_loc    = (const float*)d_in[5];
    const float* b_loc    = (const float*)d_in[6];
    const float* W_evt    = (const float*)d_in[7];
    const float* b_evt    = (const float*)d_in[8];
    const float* W_l      = (const float*)d_in[9];
    const float* b_l      = (const float*)d_in[10];
    const float* W_r      = (const float*)d_in[11];
    const float* W_h1     = (const float*)d_in[12];
    const float* b_h1     = (const float*)d_in[13];
    const float* W_h2     = (const float*)d_in[14];
    const float* b_h2     = (const float*)d_in[15];
    float* out = (float*)d_out;

    char* ws = (char*)d_ws;
    size_t off = 0;
    auto alloc = [&](size_t bytes) -> void* {
        void* p = ws + off;
        off += (bytes + 255) & ~(size_t)255;
        return p;
    };
    unsigned* evtb  = (unsigned*)alloc((size_t)N_EVT * 32 * 4);      // bf16 evt_x (12.8 MB)
    float* loc_x    = (float*)alloc((size_t)N_LOC * 64 * 4);         // 25.6 MB
    float* meanb    = (float*)alloc((size_t)N_LOC * 64 * 4);         // 25.6 MB
    unsigned* binned= (unsigned*)alloc((size_t)NB * BCAP * 4);       // 8 MB packed
    int*   deg      = (int*)alloc((size_t)N_LOC * 4);
    int*   row_ex   = (int*)alloc((size_t)(N_LOC + 1) * 4);
    int*   csr      = (int*)alloc((size_t)N_EDGE * 4);
    int*   bucket_cnt = (int*)alloc((size_t)NB * 4);
    int*   csr_off  = (int*)alloc((size_t)(NB + 1) * 4);
    (void)ws_size; (void)in_sizes; (void)n_in; (void)out_size;

    hipMemsetAsync(bucket_cnt, 0, (size_t)NB * 4, stream);

    // 25000 wave-batches of 4 rows -> 6250 blocks for dense kernels
    k_evt<<<6250, 256, 0, stream>>>(evt_feat, W_evt, b_evt, evtb, N_EVT);
    k_loc<<<6250, 256, 0, stream>>>(loc_feat, qid, emb, W_loc, b_loc, loc_x, N_LOC);
    k_bin<<<(N_EDGE + TILE - 1) / TILE, 256, 0, stream>>>(ei, bucket_cnt, binned, N_EDGE);
    k_bscan<<<1, 512, 0, stream>>>(bucket_cnt, csr_off);
    k_bfill<<<NB, 256, 0, stream>>>(bucket_cnt, csr_off, binned, deg, row_ex, csr);
    k_aggr<<<N_LOC / 4, 256, 0, stream>>>(evtb, row_ex, deg, csr, meanb, N_LOC);
    k_comb<<<6250, 256, 0, stream>>>(meanb, loc_x, W_l, b_l, W_r, W_h1, b_h1, W_h2, b_h2,
                                     out, N_LOC);
}